// Round 4
// baseline (276.506 us; speedup 1.0000x reference)
//
#include <hip/hip_runtime.h>

typedef unsigned short u16;
typedef __bf16 bf16;
typedef __bf16 bf16x8 __attribute__((ext_vector_type(8)));
typedef __bf16 bf16x4 __attribute__((ext_vector_type(4)));
typedef short s16x4 __attribute__((ext_vector_type(4)));
typedef float f32x4 __attribute__((ext_vector_type(4)));
typedef unsigned short u16x8 __attribute__((ext_vector_type(8)));
typedef unsigned short u16x4 __attribute__((ext_vector_type(4)));
typedef unsigned short u16x2 __attribute__((ext_vector_type(2)));

#define DEVI static __device__ __forceinline__

DEVI float bf2f(u16 h) { return __builtin_bit_cast(float, (unsigned)h << 16); }
DEVI u16 cvt_bf(float f) { return __builtin_bit_cast(u16, (bf16)f); }  // HW RTNE convert

// async global->LDS, 16B/lane; LDS dest = wave-uniform base, HW adds lane*16
DEVI void gload16(const u16* g, u16* l) {
  __builtin_amdgcn_global_load_lds(
      (const __attribute__((address_space(1))) void*)g,
      (__attribute__((address_space(3))) void*)l, 16, 0, 0);
}

DEVI float gelu_exact(float x) {
  return 0.5f * x * (1.0f + erff(x * 0.70710678118654752f));
}

// 16x16x16 bf16 MFMA (K=16): B-frag k-layout (g*4+j) matches QK^T C-layout -> P stays in regs.
DEVI f32x4 mfma16(bf16x4 a, bf16x4 b, f32x4 c) {
#if __has_builtin(__builtin_amdgcn_mfma_f32_16x16x16bf16_1k)
  return __builtin_amdgcn_mfma_f32_16x16x16bf16_1k(
      __builtin_bit_cast(s16x4, a), __builtin_bit_cast(s16x4, b), c, 0, 0, 0);
#else
  f32x4 r = c;
  asm volatile("s_nop 1\n\tv_mfma_f32_16x16x16_bf16 %0, %1, %2, %0\n\ts_nop 7\n\ts_nop 3"
               : "+v"(r) : "v"(a), "v"(b));
  return r;
#endif
}

// ---------------------------------------------------------------- cast fp32->bf16
__global__ __launch_bounds__(256) void k_cast(const float* __restrict__ x,
                                              const float* __restrict__ wqkv,
                                              const float* __restrict__ wout,
                                              const float* __restrict__ w1,
                                              const float* __restrict__ wv,
                                              const float* __restrict__ w2,
                                              u16* __restrict__ dst0) {
  long i = (long)blockIdx.x * 256 + threadIdx.x;
  const float* src;
  u16* dst;
  long off;
  if (i < 1048576)       { src = x;    dst = dst0;           off = i; }
  else if (i < 1097728)  { src = wqkv; dst = dst0 + 4194304; off = i - 1048576; }
  else if (i < 1114112)  { src = wout; dst = dst0 + 4390912; off = i - 1097728; }
  else if (i < 1179648)  { src = w1;   dst = dst0 + 4456448; off = i - 1114112; }
  else if (i < 1245184)  { src = wv;   dst = dst0 + 4718592; off = i - 1179648; }
  else                   { src = w2;   dst = dst0 + 4980736; off = i - 1245184; }
  float4 f = reinterpret_cast<const float4*>(src)[off];
  u16x4 o;
  o[0] = cvt_bf(f.x); o[1] = cvt_bf(f.y); o[2] = cvt_bf(f.z); o[3] = cvt_bf(f.w);
  reinterpret_cast<u16x4*>(dst)[off] = o;
}

// ---------------------------------------------------------------- GEMM: C = A * B^T (+bias)
template <int BM, int BN, int NI>
__global__ __launch_bounds__(256) void k_gemm(const u16* __restrict__ A, const u16* __restrict__ B0,
                                              const u16* __restrict__ B1, int Nsplit,
                                              const float* __restrict__ bias,
                                              u16* __restrict__ C, int N, int K) {
  constexpr int MI = BM / 32;
  __shared__ u16 Alds[BM * 64];
  __shared__ u16 Blds[BN * 64];
  const int m0 = blockIdx.x * BM;
  const int n0 = blockIdx.y * BN;
  const u16* Ap = A + (long)m0 * K;
  const u16* Bp = (n0 < Nsplit) ? (B0 + (long)n0 * K) : (B1 + (long)(n0 - Nsplit) * K);
  const int tid = threadIdx.x, lane = tid & 63, wave = tid >> 6;
  const int wr = (wave >> 1) * (BM / 2), wc = (wave & 1) * (BN / 2);
  const int lr = lane & 15, g = lane >> 4;
  const int sr = lane >> 3, sg = lane & 7;

  f32x4 acc[MI][NI] = {};
  const int nk = K >> 6;
  for (int kt = 0; kt < nk; ++kt) {
    const int kb = kt << 6;
    __syncthreads();
#pragma unroll
    for (int c = 0; c < BM / 32; ++c) {
      const int row = wave * (BM / 4) + c * 8 + sr;
      gload16(Ap + (long)row * K + kb + ((sg ^ (row & 7)) << 3),
              &Alds[(wave * (BM / 4) + c * 8) << 6]);
    }
#pragma unroll
    for (int c = 0; c < BN / 32; ++c) {
      const int row = wave * (BN / 4) + c * 8 + sr;
      gload16(Bp + (long)row * K + kb + ((sg ^ ((row / NI) & 7)) << 3),
              &Blds[(wave * (BN / 4) + c * 8) << 6]);
    }
    __syncthreads();
#pragma unroll
    for (int kk = 0; kk < 2; ++kk) {
      bf16x8 av[MI], bv[NI];
#pragma unroll
      for (int i = 0; i < MI; ++i) {
        const int ra = wr + i * 16 + lr;
        av[i] = *reinterpret_cast<const bf16x8*>(&Alds[(ra << 6) + (((kk * 4 + g) ^ (ra & 7)) << 3)]);
      }
#pragma unroll
      for (int ni = 0; ni < NI; ++ni) {
        const int rb = wc + lr * NI + ni;
        bv[ni] = *reinterpret_cast<const bf16x8*>(&Blds[(rb << 6) + (((kk * 4 + g) ^ ((rb / NI) & 7)) << 3)]);
      }
#pragma unroll
      for (int mi = 0; mi < MI; ++mi)
#pragma unroll
        for (int ni = 0; ni < NI; ++ni)
          acc[mi][ni] = __builtin_amdgcn_mfma_f32_16x16x32_bf16(av[mi], bv[ni], acc[mi][ni], 0, 0, 0);
    }
  }
  const int colb = n0 + wc + lr * NI;
  float bvv[NI];
#pragma unroll
  for (int ni = 0; ni < NI; ++ni) bvv[ni] = bias ? bias[colb + ni] : 0.0f;
#pragma unroll
  for (int mi = 0; mi < MI; ++mi) {
#pragma unroll
    for (int r = 0; r < 4; ++r) {
      const long row = m0 + wr + mi * 16 + g * 4 + r;
      if constexpr (NI == 4) {
        u16x4 v;
#pragma unroll
        for (int ni = 0; ni < 4; ++ni) v[ni] = cvt_bf(acc[mi][ni][r] + bvv[ni]);
        *reinterpret_cast<u16x4*>(C + row * N + colb) = v;
      } else {
        u16x2 v;
#pragma unroll
        for (int ni = 0; ni < 2; ++ni) v[ni] = cvt_bf(acc[mi][ni][r] + bvv[ni]);
        *reinterpret_cast<u16x2*>(C + row * N + colb) = v;
      }
    }
  }
}

// ---------------------------------------------------------------- GEGLU-fused FFN-up
__global__ __launch_bounds__(256) void k_glu(const u16* __restrict__ A, const u16* __restrict__ W1,
                                             const u16* __restrict__ Wv, u16* __restrict__ C) {
  constexpr int K = 256, N = 1024;
  __shared__ u16 Alds[128 * 64];
  __shared__ u16 Blds[64 * 64];
  const int m0 = blockIdx.x * 128;
  const int n0h = blockIdx.y * 32;
  const u16* Ap = A + (long)m0 * K;
  const int tid = threadIdx.x, lane = tid & 63, wave = tid >> 6;
  const int lr = lane & 15, g = lane >> 4;
  const int sr = lane >> 3, sg = lane & 7;

  f32x4 acc[2][4] = {};
  for (int kt = 0; kt < 4; ++kt) {
    const int kb = kt << 6;
    __syncthreads();
#pragma unroll
    for (int c = 0; c < 4; ++c) {
      const int row = wave * 32 + c * 8 + sr;
      gload16(Ap + (long)row * K + kb + ((sg ^ (row & 7)) << 3), &Alds[(wave * 32 + c * 8) << 6]);
    }
#pragma unroll
    for (int c = 0; c < 2; ++c) {
      const int row = wave * 16 + c * 8 + sr;
      const u16* bp = (row & 1) ? Wv : W1;
      gload16(bp + (long)(n0h + (row >> 1)) * K + kb + ((sg ^ ((row >> 2) & 7)) << 3),
              &Blds[(wave * 16 + c * 8) << 6]);
    }
    __syncthreads();
#pragma unroll
    for (int kk = 0; kk < 2; ++kk) {
      bf16x8 av[2], bv[4];
#pragma unroll
      for (int i = 0; i < 2; ++i) {
        const int ra = wave * 32 + i * 16 + lr;
        av[i] = *reinterpret_cast<const bf16x8*>(&Alds[(ra << 6) + (((kk * 4 + g) ^ (ra & 7)) << 3)]);
      }
#pragma unroll
      for (int ni = 0; ni < 4; ++ni) {
        const int rb = lr * 4 + ni;
        bv[ni] = *reinterpret_cast<const bf16x8*>(&Blds[(rb << 6) + (((kk * 4 + g) ^ ((rb >> 2) & 7)) << 3)]);
      }
#pragma unroll
      for (int mi = 0; mi < 2; ++mi)
#pragma unroll
        for (int ni = 0; ni < 4; ++ni)
          acc[mi][ni] = __builtin_amdgcn_mfma_f32_16x16x32_bf16(av[mi], bv[ni], acc[mi][ni], 0, 0, 0);
    }
  }
  const int j0 = n0h + lr * 2;
#pragma unroll
  for (int mi = 0; mi < 2; ++mi) {
#pragma unroll
    for (int r = 0; r < 4; ++r) {
      const long row = m0 + wave * 32 + mi * 16 + g * 4 + r;
      u16x2 v;
      v[0] = cvt_bf(gelu_exact(acc[mi][0][r]) * acc[mi][1][r]);
      v[1] = cvt_bf(gelu_exact(acc[mi][2][r]) * acc[mi][3][r]);
      *reinterpret_cast<u16x2*>(C + row * N + j0) = v;
    }
  }
}

// ---------------------------------------------------------------- V transpose: vt[(bh*32+d)*2048+n]
__global__ __launch_bounds__(256) void k_vt(const u16* __restrict__ qkv, u16* __restrict__ vt) {
  const int bh = blockIdx.x & 63, nt = blockIdx.x >> 6;
  const int b = bh >> 3, h = bh & 7;
  const int wave = threadIdx.x >> 6, lane = threadIdx.x & 63;
  const int dcol = wave * 8;
#pragma unroll
  for (int i = 0; i < 4; ++i) {
    const int nn = nt * 256 + i * 64 + lane;
    u16x8 v = *reinterpret_cast<const u16x8*>(qkv + (long)(b * 2048 + nn) * 768 + 512 + h * 32 + dcol);
#pragma unroll
    for (int j = 0; j < 8; ++j)
      vt[(long)(bh * 32 + dcol + j) * 2048 + nn] = v[j];
  }
}

// ---------------------------------------------------------------- flash attention
// KVBLK=128, 8 waves x 16 q-rows. Swapped QK^T (16x16x32); PV + row-sum via 16x16x16
// MFMAs whose B-frag layout matches the QK C-layout -> P never leaves registers.
// T13 defer-max: rescale branch only when __any(tmax > m+8). l accumulated by ones-MFMA.
// K: Klds [64r][8 gran16], granule^(r&7) swizzle. V: Vlds [32d][128k], 8B-granule^((d&3)<<2)
// swizzle; both staged via global_load_lds from pre-swizzled global addrs (rule #21).
__global__ __launch_bounds__(512) void k_attn(const u16* __restrict__ qkv, const u16* __restrict__ vt,
                                              u16* __restrict__ o) {
  __shared__ u16 Klds[2 * 4096];
  __shared__ u16 Vlds[2 * 4096];
  const int id = blockIdx.x;
  const int qt = id >> 6, bh = id & 63;
  const int b = bh >> 3, h = bh & 7;
  const int tid = threadIdx.x, wave = tid >> 6, lane = tid & 63;
  const int lq = lane & 15, g = lane >> 4, lqh = lq & 7;

  const long qrow = (long)(b * 2048 + qt * 128 + wave * 16 + lq);
  u16x8 qraw = *reinterpret_cast<const u16x8*>(qkv + qrow * 768 + h * 32 + g * 8);
  bf16x8 qf;
#pragma unroll
  for (int j = 0; j < 8; ++j) qf[j] = (bf16)(bf2f(qraw[j]) * 0.25503486f);  // hd^-.5 * log2e

  // staging sources (pre-swizzled globals)
  const int rK = tid >> 3, gpK = tid & 7, lK = gpK ^ (rK & 7);
  const u16* ksrc = qkv + (long)(b * 2048 + (lK >> 2) * 64 + rK) * 768 + 256 + h * 32 + (lK & 3) * 8;
  const int dV = tid >> 4, gpV = tid & 15, lgV = gpV ^ ((dV & 3) << 1);  // 16B-granule swizzle
  const u16* vsrc = vt + (long)(bh * 32 + dV) * 2048 + lgV * 8;
  u16* kdst = Klds + wave * 512;
  u16* vdst = Vlds + wave * 512;

  gload16(ksrc, kdst);
  gload16(vsrc, vdst);

  float m = -1e30f;
  f32x4 oacc[2] = {};
  f32x4 lacc = {};
  const f32x4 zero = {0.0f, 0.0f, 0.0f, 0.0f};
  bf16x4 onesf;
  onesf[0] = onesf[1] = onesf[2] = onesf[3] = (bf16)1.0f;

  for (int kt = 0; kt < 16; ++kt) {
    const int bo = (kt & 1) * 4096;
    __syncthreads();
    if (kt + 1 < 16) {
      const int nbo = ((kt + 1) & 1) * 4096;
      gload16(ksrc + (long)(kt + 1) * 98304, kdst + nbo);
      gload16(vsrc + (kt + 1) * 128, vdst + nbo);
    }
    // QK^T: s[f][r] = S[k = (f>>2)*64 + (f&3)*16 + g*4 + r][q = lq]
    f32x4 s[8];
#pragma unroll
    for (int f = 0; f < 8; ++f) {
      const bf16x8 kf = *reinterpret_cast<const bf16x8*>(
          &Klds[bo + (((f & 3) * 16 + lq) << 6) + ((((f >> 2) * 4 + g) ^ lqh) << 3)]);
      s[f] = __builtin_amdgcn_mfma_f32_16x16x32_bf16(kf, qf, zero, 0, 0, 0);
    }
    // defer-max: common path has no cross-lane reduce, no rescale
    float tmax = -1e30f;
#pragma unroll
    for (int f = 0; f < 8; ++f) {
      const float m01 = fmaxf(s[f][0], s[f][1]);
      const float m23 = fmaxf(s[f][2], s[f][3]);
      tmax = fmaxf(tmax, fmaxf(m01, m23));
    }
    if (__any(tmax > m + 8.0f)) {
      tmax = fmaxf(tmax, __shfl_xor(tmax, 16));
      tmax = fmaxf(tmax, __shfl_xor(tmax, 32));
      const float mnew = fmaxf(m, tmax);
      const float alpha = exp2f(m - mnew);
#pragma unroll
      for (int di = 0; di < 2; ++di)
#pragma unroll
        for (int r = 0; r < 4; ++r) oacc[di][r] *= alpha;
#pragma unroll
      for (int r = 0; r < 4; ++r) lacc[r] *= alpha;
      m = mnew;
    }
    // p = exp2(s - m)  (bounded by 2^8)
#pragma unroll
    for (int f = 0; f < 8; ++f)
#pragma unroll
      for (int r = 0; r < 4; ++r) s[f][r] = exp2f(s[f][r] - m);

    // PV + row-sum: P stays in registers (B-frag of 16x16x16 = QK C-layout)
#pragma unroll
    for (int f = 0; f < 8; ++f) {
      bf16x4 pf4;
      pf4[0] = (bf16)s[f][0]; pf4[1] = (bf16)s[f][1];
      pf4[2] = (bf16)s[f][2]; pf4[3] = (bf16)s[f][3];
      lacc = mfma16(onesf, pf4, lacc);
      const int gl8 = (f >> 2) * 16 + (f & 3) * 4 + g;          // logical 8B granule
      const int ph8 = gl8 ^ ((lq & 3) << 2);                    // bank swizzle
#pragma unroll
      for (int di = 0; di < 2; ++di) {
        const int d = di * 16 + lq;
        const bf16x4 vf = *reinterpret_cast<const bf16x4*>(&Vlds[bo + d * 128 + ph8 * 4]);
        oacc[di] = mfma16(vf, pf4, oacc[di]);
      }
    }
  }

  const float inv = 1.0f / lacc[0];
  const long orow = (long)(b * 2048 + qt * 128 + wave * 16 + lq);
#pragma unroll
  for (int di = 0; di < 2; ++di) {
    u16x4 ov;
#pragma unroll
    for (int r = 0; r < 4; ++r) ov[r] = cvt_bf(oacc[di][r] * inv);
    *reinterpret_cast<u16x4*>(o + orow * 256 + h * 32 + di * 16 + g * 4) = ov;
  }
}

// ---------------------------------------------------------------- LayerNorm(yin_bf16 + xres_f32)
__global__ __launch_bounds__(256) void k_ln(const u16* __restrict__ yin, const float* __restrict__ xres,
                                            const float* __restrict__ gw, const float* __restrict__ bw,
                                            float* __restrict__ out) {
  const int row = blockIdx.x * 4 + (threadIdx.x >> 6);
  const int lane = threadIdx.x & 63;
  const long base = (long)row * 256 + lane * 4;
  const float4 xv = *reinterpret_cast<const float4*>(xres + base);
  const u16x4 yv = *reinterpret_cast<const u16x4*>(yin + base);
  float s0 = bf2f(yv[0]) + xv.x;
  float s1 = bf2f(yv[1]) + xv.y;
  float s2 = bf2f(yv[2]) + xv.z;
  float s3 = bf2f(yv[3]) + xv.w;
  float sum = s0 + s1 + s2 + s3;
  float sq = s0 * s0 + s1 * s1 + s2 * s2 + s3 * s3;
#pragma unroll
  for (int msk = 1; msk < 64; msk <<= 1) {
    sum += __shfl_xor(sum, msk);
    sq += __shfl_xor(sq, msk);
  }
  const float mean = sum * (1.0f / 256.0f);
  const float var = sq * (1.0f / 256.0f) - mean * mean;
  const float rstd = rsqrtf(var + 1e-5f);
  const int c = lane * 4;
  float4 ov;
  ov.x = (s0 - mean) * rstd * gw[c + 0] + bw[c + 0];
  ov.y = (s1 - mean) * rstd * gw[c + 1] + bw[c + 1];
  ov.z = (s2 - mean) * rstd * gw[c + 2] + bw[c + 2];
  ov.w = (s3 - mean) * rstd * gw[c + 3] + bw[c + 3];
  *reinterpret_cast<float4*>(out + base) = ov;
}

// ---------------------------------------------------------------- launch
extern "C" void kernel_launch(void* const* d_in, const int* in_sizes, int n_in,
                              void* d_out, int out_size, void* d_ws, size_t ws_size,
                              hipStream_t stream) {
  (void)in_sizes; (void)n_in; (void)out_size;
  if (ws_size < 136314880ULL) return;

  const float* x     = (const float*)d_in[0];
  const float* w_qkv = (const float*)d_in[1];
  const float* w_out = (const float*)d_in[2];
  const float* b_out = (const float*)d_in[3];
  const float* w1    = (const float*)d_in[4];
  const float* wv    = (const float*)d_in[5];
  const float* w2    = (const float*)d_in[6];
  const float* ln1g  = (const float*)d_in[7];
  const float* ln1b  = (const float*)d_in[8];
  const float* ln2g  = (const float*)d_in[9];
  const float* ln2b  = (const float*)d_in[10];
  float* outp = (float*)d_out;

  char* ws = (char*)d_ws;
  u16* xb    = (u16*)ws;
  u16* wqkvb = xb + 4194304;
  u16* woutb = wqkvb + 196608;
  u16* w1b   = woutb + 65536;
  u16* wvb   = w1b + 262144;
  u16* w2b   = wvb + 262144;
  u16* qkvb  = w2b + 262144;
  u16* ob    = qkvb + 12582912;
  u16* yb    = ob + 4194304;
  float* x1  = (float*)(ws + 52428800);
  u16* vtb   = (u16*)(ws + 69206016);
  u16* ffin  = qkvb;
  u16* ff2   = xb;

  k_cast<<<5120, 256, 0, stream>>>(x, w_qkv, w_out, w1, wv, w2, xb);
  k_gemm<128, 128, 4><<<dim3(128, 6), 256, 0, stream>>>(xb, wqkvb, wqkvb, 1 << 30, nullptr, qkvb, 768, 256);
  k_vt<<<512, 256, 0, stream>>>(qkvb, vtb);
  k_attn<<<1024, 512, 0, stream>>>(qkvb, vtb, ob);
  k_gemm<128, 64, 2><<<dim3(128, 4), 256, 0, stream>>>(ob, woutb, woutb, 1 << 30, b_out, yb, 256, 256);
  k_ln<<<4096, 256, 0, stream>>>(yb, x, ln1g, ln1b, x1);
  k_glu<<<dim3(128, 32), 256, 0, stream>>>(yb, w1b, wvb, ffin);
  k_gemm<128, 64, 2><<<dim3(128, 4), 256, 0, stream>>>(ffin, w2b, w2b, 1 << 30, nullptr, ff2, 256, 1024);
  k_ln<<<4096, 256, 0, stream>>>(ff2, x1, ln2g, ln2b, outp);
}